// Round 1
// baseline (307.912 us; speedup 1.0000x reference)
//
#include <hip/hip_runtime.h>

// Problem constants (fixed by setup_inputs)
#define BB   4
#define HH   640
#define WW   640
#define NLB  10
#define HWSZ (HH * WW)   // 409600

// |sobel_x| + |sobel_y| of a 3x3 neighborhood a[row][col]
__device__ __forceinline__ float sob3(const float a[3][3]) {
    float gx = (a[0][2] - a[0][0]) + 2.0f * (a[1][2] - a[1][0]) + (a[2][2] - a[2][0]);
    float gy = (a[0][0] + 2.0f * a[0][1] + a[0][2]) - (a[2][0] + 2.0f * a[2][1] + a[2][2]);
    return fabsf(gx) + fabsf(gy);
}

// Block-wide reduction of two floats, then one atomicAdd per block per value.
// All 256 threads must call this.
__device__ __forceinline__ void block_reduce2_atomic(float v0, float v1,
                                                     float* dst0, float* dst1) {
    #pragma unroll
    for (int off = 32; off > 0; off >>= 1) {
        v0 += __shfl_down(v0, off);
        v1 += __shfl_down(v1, off);
    }
    __shared__ float s0[4], s1[4];
    int lane = threadIdx.x & 63;
    int wid  = threadIdx.x >> 6;
    if (lane == 0) { s0[wid] = v0; s1[wid] = v1; }
    __syncthreads();
    if (threadIdx.x == 0) {
        float t0 = s0[0] + s0[1] + s0[2] + s0[3];
        float t1 = s1[0] + s1[1] + s1[2] + s1[3];
        atomicAdd(dst0, t0);
        atomicAdd(dst1, t1);
    }
}

// ---------------- Kernel A: global loss sums ----------------
// grid = (HW/256, B), block = 256. accum[b*2+0] = sum |gen - max(y, mean)|,
// accum[b*2+1] = sum |sob(gen) - max(sob(y), sob(mean))|
__global__ __launch_bounds__(256) void kglobal(const float* __restrict__ vis,
                                               const float* __restrict__ th,
                                               const float* __restrict__ gen,
                                               float* __restrict__ accum) {
    int b = blockIdx.y;
    int p = blockIdx.x * 256 + threadIdx.x;
    float t_in = 0.0f, t_gr = 0.0f;
    if (p < HWSZ) {
        int r = p / WW, c = p % WW;
        const float* v = vis + b * HWSZ;
        const float* t = th  + b * HWSZ;
        const float* g = gen + b * HWSZ;
        float av[3][3], am[3][3], ag[3][3];
        #pragma unroll
        for (int i = 0; i < 3; i++) {
            int rr = r - 1 + i;
            bool rok = (rr >= 0) && (rr < HH);
            #pragma unroll
            for (int j = 0; j < 3; j++) {
                int cc = c - 1 + j;
                bool ok = rok && (cc >= 0) && (cc < WW);
                int idx = rr * WW + cc;
                float fv = ok ? v[idx] : 0.0f;
                float ft = ok ? t[idx] : 0.0f;
                float fg = ok ? g[idx] : 0.0f;
                av[i][j] = fv;
                am[i][j] = 0.5f * fv + 0.5f * ft;
                ag[i][j] = fg;
            }
        }
        float yc = av[1][1], mc = am[1][1], gc = ag[1][1];
        t_in = fabsf(gc - fmaxf(yc, mc));
        float yg = sob3(av), mg = sob3(am), gg = sob3(ag);
        t_gr = fabsf(gg - fmaxf(yg, mg));
    }
    block_reduce2_atomic(t_in, t_gr, &accum[b * 2 + 0], &accum[b * 2 + 1]);
}

// ---------------- Kernel B: per-box masked loss sums ----------------
// grid = (CHUNKS, B*NL), block = 256.
// boxacc[box*2+0] = sum_in_box |sob(m_gen) - max(sob(m_vis), sob(m_mean7))|
// boxacc[box*2+1] = sum_in_box |m_gen - max(m_vis, m_mean7)|
__global__ __launch_bounds__(256) void kbox(const float* __restrict__ vis,
                                            const float* __restrict__ th,
                                            const float* __restrict__ gen,
                                            const int* __restrict__ label,
                                            float* __restrict__ boxacc) {
    int box = blockIdx.y;
    int b   = box / NLB;
    const int* lb = label + box * 5;
    int x1 = lb[1], y1 = lb[2], x2 = lb[3], y2 = lb[4];
    int bw = x2 - x1, bh = y2 - y1;
    int npix = (bw > 0 && bh > 0) ? bw * bh : 0;
    const float* v = vis + b * HWSZ;
    const float* t = th  + b * HWSZ;
    const float* g = gen + b * HWSZ;
    float s0 = 0.0f, s1 = 0.0f;
    int stride = gridDim.x * blockDim.x;
    for (int q = blockIdx.x * blockDim.x + threadIdx.x; q < npix; q += stride) {
        int r = y1 + q / bw;
        int c = x1 + q % bw;
        float av[3][3], am[3][3], ag[3][3];
        #pragma unroll
        for (int i = 0; i < 3; i++) {
            int rr = r - 1 + i;
            bool rok = (rr >= y1) && (rr < y2);
            #pragma unroll
            for (int j = 0; j < 3; j++) {
                int cc = c - 1 + j;
                bool ok = rok && (cc >= x1) && (cc < x2);
                int idx = rr * WW + cc;
                float fv = ok ? v[idx] : 0.0f;
                float ft = ok ? t[idx] : 0.0f;
                float fg = ok ? g[idx] : 0.0f;
                av[i][j] = fv;
                am[i][j] = 0.3f * fv + 0.7f * ft;
                ag[i][j] = fg;
            }
        }
        float gv = sob3(av), gm = sob3(am), gg = sob3(ag);
        s0 += fabsf(gg - fmaxf(gv, gm));
        s1 += fabsf(ag[1][1] - fmaxf(av[1][1], am[1][1]));
    }
    block_reduce2_atomic(s0, s1, &boxacc[box * 2 + 0], &boxacc[box * 2 + 1]);
}

// ---------------- Kernel C: finalize all 7 outputs ----------------
// out layout (flat, return order): loss_ss[4], loss_global[4], loss_label[4],
//                                  loss_in[4], loss_grad[4], ls[4], lin[4]
__global__ __launch_bounds__(64) void kfin(const float* __restrict__ accum,
                                           const float* __restrict__ boxacc,
                                           const int* __restrict__ label,
                                           const float* __restrict__ bptr,
                                           const float* __restrict__ cptr,
                                           float* __restrict__ out) {
    __shared__ float Ls[BB * NLB], L1[BB * NLB];
    int tid = threadIdx.x;
    if (tid < BB * NLB) {
        const int* lb = label + tid * 5;
        int x1 = lb[1], y1 = lb[2], x2 = lb[3], y2 = lb[4];
        bool valid = !((x1 == 0) && (y1 == 0) && (x2 == 0) && (y2 == 0));
        float area = (float)((y2 - y1) * (x2 - x1));  // * C, C==1
        float safe_area = fmaxf(area, 1.0f);
        float vv = valid ? 1.0f : 0.0f;
        Ls[tid] = boxacc[tid * 2 + 0] / safe_area * vv;
        L1[tid] = boxacc[tid * 2 + 1] / safe_area * vv;
    }
    __syncthreads();
    if (tid < BB) {
        float alpha = bptr[0];
        float beta  = cptr[0];
        float cnt = 0.0f, sls = 0.0f, slin = 0.0f;
        for (int nl = 0; nl < NLB; nl++) {
            float a = Ls[tid * NLB + nl];
            float l = L1[tid * NLB + nl];
            if (a != 0.0f || l != 0.0f) cnt += 1.0f;
            sls  += a;
            slin += l;
        }
        float safe_cnt = fmaxf(cnt, 1.0f);
        float ls  = (cnt > 0.0f) ? (sls  / safe_cnt) : 0.0f;
        float lin = (cnt > 0.0f) ? (slin / safe_cnt) : 0.0f;
        float loss_label = (1.0f - beta) * ls + beta * lin;
        float loss_in   = accum[tid * 2 + 0] * (1.0f / (float)HWSZ);
        float loss_grad = accum[tid * 2 + 1] * (1.0f / (float)HWSZ);
        float loss_global = alpha * loss_in + (1.0f - alpha) * loss_grad;
        out[0      + tid] = 0.0f;          // loss_ss
        out[BB     + tid] = loss_global;
        out[2 * BB + tid] = loss_label;
        out[3 * BB + tid] = loss_in;
        out[4 * BB + tid] = loss_grad;
        out[5 * BB + tid] = ls;
        out[6 * BB + tid] = lin;
    }
}

extern "C" void kernel_launch(void* const* d_in, const int* in_sizes, int n_in,
                              void* d_out, int out_size, void* d_ws, size_t ws_size,
                              hipStream_t stream) {
    const float* bptr  = (const float*)d_in[0];
    const float* cptr  = (const float*)d_in[1];
    const float* vis   = (const float*)d_in[2];
    // d_in[3] = image_ir (unused by the reference)
    const float* gen   = (const float*)d_in[4];
    const int*   label = (const int*)d_in[5];
    const float* th    = (const float*)d_in[6];
    float* out = (float*)d_out;

    float* accum  = (float*)d_ws;       // 8 floats:  [b*2+{in,grad}]
    float* boxacc = accum + 8;          // 80 floats: [box*2+{Lssim,L1}]
    hipMemsetAsync(d_ws, 0, 88 * sizeof(float), stream);

    dim3 gA((HWSZ + 255) / 256, BB);
    kglobal<<<gA, 256, 0, stream>>>(vis, th, gen, accum);

    dim3 gB(128, BB * NLB);
    kbox<<<gB, 256, 0, stream>>>(vis, th, gen, label, boxacc);

    kfin<<<1, 64, 0, stream>>>(accum, boxacc, label, bptr, cptr, out);
}

// Round 3
// 138.082 us; speedup vs baseline: 2.2299x; 2.2299x over previous
//
#include <hip/hip_runtime.h>

// Problem constants (fixed by setup_inputs)
#define BB   4
#define HH   640
#define WW   640
#define NLB  10
#define HWSZ (HH * WW)   // 409600
#define PR   8           // rows per thread-strip (global kernel)
#define PBX  8           // rows per band (box kernel)

// Block-wide reduction of two floats, then one atomicAdd per block per value.
// All threads of the block must call this.
__device__ __forceinline__ void block_reduce2_atomic(float v0, float v1,
                                                     float* dst0, float* dst1) {
    #pragma unroll
    for (int off = 32; off > 0; off >>= 1) {
        v0 += __shfl_down(v0, off);
        v1 += __shfl_down(v1, off);
    }
    __shared__ float s0[4], s1[4];
    int lane = threadIdx.x & 63;
    int wid  = threadIdx.x >> 6;
    if (lane == 0) { s0[wid] = v0; s1[wid] = v1; }
    __syncthreads();
    if (threadIdx.x == 0) {
        float t0 = s0[0] + s0[1] + s0[2] + s0[3];
        float t1 = s1[0] + s1[1] + s1[2] + s1[3];
        atomicAdd(dst0, t0);
        atomicAdd(dst1, t1);
    }
}

// ---------------- Kernel A: global loss sums (rolling-window strips) --------
// grid = (3 * HH/PR, B), block = 256. Thread owns column c, walks PR rows.
// Per row keep (hx = R-L, hy = L+2C+R, center) per plane; sobel at row r:
//   gx = hx[r-1] + 2*hx[r] + hx[r+1];  gy = hy[r-1] - hy[r+1]
// NOTE: only center pixels with c < WW may contribute (sobel at c==WW is
// nonzero from the c==WW-1 neighbor, but that pixel doesn't exist).
__global__ __launch_bounds__(256) void kglobal(const float* __restrict__ vis,
                                               const float* __restrict__ th,
                                               const float* __restrict__ gen,
                                               float* __restrict__ accum) {
    const int b  = blockIdx.y;
    const int xt = blockIdx.x % 3;
    const int rb = blockIdx.x / 3;
    const int c  = xt * 256 + threadIdx.x;   // [0, 768); >=640 lanes contribute 0
    const int r0 = rb * PR;
    const float* v = vis + b * HWSZ;
    const float* t = th  + b * HWSZ;
    const float* g = gen + b * HWSZ;
    const bool okL = (c >= 1) && (c - 1 < WW);
    const bool okC = (c < WW);
    const bool okR = (c + 1 < WW);
    const float inb = okC ? 1.0f : 0.0f;     // fmask for the center pixel

    float hxv[3], hyv[3], cvv[3];
    float hxm[3], hym[3], cmm[3];
    float hxg[3], hyg[3], cgg[3];

    auto loadrow = [&](int rr, int w) {
        const bool rok = ((unsigned)rr < (unsigned)HH);
        const int base = rr * WW + c;
        float vL = (rok && okL) ? v[base - 1] : 0.0f;
        float vC = (rok && okC) ? v[base    ] : 0.0f;
        float vR = (rok && okR) ? v[base + 1] : 0.0f;
        float tL = (rok && okL) ? t[base - 1] : 0.0f;
        float tC = (rok && okC) ? t[base    ] : 0.0f;
        float tR = (rok && okR) ? t[base + 1] : 0.0f;
        float gL = (rok && okL) ? g[base - 1] : 0.0f;
        float gC = (rok && okC) ? g[base    ] : 0.0f;
        float gR = (rok && okR) ? g[base + 1] : 0.0f;
        float mL = 0.5f * vL + 0.5f * tL;
        float mC = 0.5f * vC + 0.5f * tC;
        float mR = 0.5f * vR + 0.5f * tR;
        hxv[w] = vR - vL; hyv[w] = vL + 2.0f * vC + vR; cvv[w] = vC;
        hxm[w] = mR - mL; hym[w] = mL + 2.0f * mC + mR; cmm[w] = mC;
        hxg[w] = gR - gL; hyg[w] = gL + 2.0f * gC + gR; cgg[w] = gC;
    };

    loadrow(r0 - 1, 0);
    loadrow(r0,     1);
    float t_in = 0.0f, t_gr = 0.0f;
    #pragma unroll
    for (int s = 0; s < PR; ++s) {
        loadrow(r0 + 1 + s, (2 + s) % 3);
        const int ia = s % 3, ib = (s + 1) % 3, ic = (s + 2) % 3;
        float sv = fabsf(hxv[ia] + 2.0f * hxv[ib] + hxv[ic]) + fabsf(hyv[ia] - hyv[ic]);
        float sm = fabsf(hxm[ia] + 2.0f * hxm[ib] + hxm[ic]) + fabsf(hym[ia] - hym[ic]);
        float sg = fabsf(hxg[ia] + 2.0f * hxg[ib] + hxg[ic]) + fabsf(hyg[ia] - hyg[ic]);
        t_gr += inb * fabsf(sg - fmaxf(sv, sm));
        t_in += inb * fabsf(cgg[ib] - fmaxf(cvv[ib], cmm[ib]));
    }
    block_reduce2_atomic(t_in, t_gr, &accum[b * 2 + 0], &accum[b * 2 + 1]);
}

// ---------------- Kernel B: per-box masked loss sums (rolling-window) -------
// grid = (40 bands, B*NL), block = 256. Band covers PBX rows of the box;
// threads span columns in chunks of 256. Zero-padding at box edges == mask,
// BUT only center pixels strictly inside [y1,y2)x[x1,x2) contribute (fmask).
__global__ __launch_bounds__(256) void kbox(const float* __restrict__ vis,
                                            const float* __restrict__ th,
                                            const float* __restrict__ gen,
                                            const int* __restrict__ label,
                                            float* __restrict__ boxacc) {
    const int box = blockIdx.y;
    const int b   = box / NLB;
    const int* lb = label + box * 5;
    const int x1 = lb[1], y1 = lb[2], x2 = lb[3], y2 = lb[4];
    const int r0 = y1 + blockIdx.x * PBX;
    if (r0 >= y2) return;   // block-uniform: band beyond box (or invalid box)

    const float* v = vis + b * HWSZ;
    const float* t = th  + b * HWSZ;
    const float* g = gen + b * HWSZ;

    float s_gr = 0.0f, s_in = 0.0f;
    for (int cb = x1; cb < x2; cb += 256) {
        const int c = cb + (int)threadIdx.x;
        const bool okL = (c - 1 >= x1) && (c - 1 < x2);
        const bool okC = (c < x2);            // c >= x1 always
        const bool okR = (c + 1 < x2);

        float hxv[3], hyv[3], cvv[3];
        float hxm[3], hym[3], cmm[3];
        float hxg[3], hyg[3], cgg[3];

        auto loadrow = [&](int rr, int w) {
            const bool rok = (rr >= y1) && (rr < y2);
            const int base = rr * WW + c;
            float vL = (rok && okL) ? v[base - 1] : 0.0f;
            float vC = (rok && okC) ? v[base    ] : 0.0f;
            float vR = (rok && okR) ? v[base + 1] : 0.0f;
            float tL = (rok && okL) ? t[base - 1] : 0.0f;
            float tC = (rok && okC) ? t[base    ] : 0.0f;
            float tR = (rok && okR) ? t[base + 1] : 0.0f;
            float gL = (rok && okL) ? g[base - 1] : 0.0f;
            float gC = (rok && okC) ? g[base    ] : 0.0f;
            float gR = (rok && okR) ? g[base + 1] : 0.0f;
            float mL = 0.3f * vL + 0.7f * tL;
            float mC = 0.3f * vC + 0.7f * tC;
            float mR = 0.3f * vR + 0.7f * tR;
            hxv[w] = vR - vL; hyv[w] = vL + 2.0f * vC + vR; cvv[w] = vC;
            hxm[w] = mR - mL; hym[w] = mL + 2.0f * mC + mR; cmm[w] = mC;
            hxg[w] = gR - gL; hyg[w] = gL + 2.0f * gC + gR; cgg[w] = gC;
        };

        loadrow(r0 - 1, 0);
        loadrow(r0,     1);
        #pragma unroll
        for (int s = 0; s < PBX; ++s) {
            loadrow(r0 + 1 + s, (2 + s) % 3);
            const int ia = s % 3, ib = (s + 1) % 3, ic = (s + 2) % 3;
            // fmask: center pixel must be inside the box
            const float inb = (okC && (r0 + s < y2)) ? 1.0f : 0.0f;
            float sv = fabsf(hxv[ia] + 2.0f * hxv[ib] + hxv[ic]) + fabsf(hyv[ia] - hyv[ic]);
            float sm = fabsf(hxm[ia] + 2.0f * hxm[ib] + hxm[ic]) + fabsf(hym[ia] - hym[ic]);
            float sg = fabsf(hxg[ia] + 2.0f * hxg[ib] + hxg[ic]) + fabsf(hyg[ia] - hyg[ic]);
            s_gr += inb * fabsf(sg - fmaxf(sv, sm));
            s_in += inb * fabsf(cgg[ib] - fmaxf(cvv[ib], cmm[ib]));
        }
    }
    block_reduce2_atomic(s_gr, s_in, &boxacc[box * 2 + 0], &boxacc[box * 2 + 1]);
}

// ---------------- Kernel C: finalize all 7 outputs ----------------
// out layout (flat, return order): loss_ss[4], loss_global[4], loss_label[4],
//                                  loss_in[4], loss_grad[4], ls[4], lin[4]
__global__ __launch_bounds__(64) void kfin(const float* __restrict__ accum,
                                           const float* __restrict__ boxacc,
                                           const int* __restrict__ label,
                                           const float* __restrict__ bptr,
                                           const float* __restrict__ cptr,
                                           float* __restrict__ out) {
    __shared__ float Ls[BB * NLB], L1[BB * NLB];
    int tid = threadIdx.x;
    if (tid < BB * NLB) {
        const int* lb = label + tid * 5;
        int x1 = lb[1], y1 = lb[2], x2 = lb[3], y2 = lb[4];
        bool valid = !((x1 == 0) && (y1 == 0) && (x2 == 0) && (y2 == 0));
        float area = (float)((y2 - y1) * (x2 - x1));  // * C, C==1
        float safe_area = fmaxf(area, 1.0f);
        float vv = valid ? 1.0f : 0.0f;
        Ls[tid] = boxacc[tid * 2 + 0] / safe_area * vv;
        L1[tid] = boxacc[tid * 2 + 1] / safe_area * vv;
    }
    __syncthreads();
    if (tid < BB) {
        float alpha = bptr[0];
        float beta  = cptr[0];
        float cnt = 0.0f, sls = 0.0f, slin = 0.0f;
        for (int nl = 0; nl < NLB; nl++) {
            float a = Ls[tid * NLB + nl];
            float l = L1[tid * NLB + nl];
            if (a != 0.0f || l != 0.0f) cnt += 1.0f;
            sls  += a;
            slin += l;
        }
        float safe_cnt = fmaxf(cnt, 1.0f);
        float ls  = (cnt > 0.0f) ? (sls  / safe_cnt) : 0.0f;
        float lin = (cnt > 0.0f) ? (slin / safe_cnt) : 0.0f;
        float loss_label = (1.0f - beta) * ls + beta * lin;
        float loss_in   = accum[tid * 2 + 0] * (1.0f / (float)HWSZ);
        float loss_grad = accum[tid * 2 + 1] * (1.0f / (float)HWSZ);
        float loss_global = alpha * loss_in + (1.0f - alpha) * loss_grad;
        out[0      + tid] = 0.0f;          // loss_ss
        out[BB     + tid] = loss_global;
        out[2 * BB + tid] = loss_label;
        out[3 * BB + tid] = loss_in;
        out[4 * BB + tid] = loss_grad;
        out[5 * BB + tid] = ls;
        out[6 * BB + tid] = lin;
    }
}

extern "C" void kernel_launch(void* const* d_in, const int* in_sizes, int n_in,
                              void* d_out, int out_size, void* d_ws, size_t ws_size,
                              hipStream_t stream) {
    const float* bptr  = (const float*)d_in[0];
    const float* cptr  = (const float*)d_in[1];
    const float* vis   = (const float*)d_in[2];
    // d_in[3] = image_ir (unused by the reference)
    const float* gen   = (const float*)d_in[4];
    const int*   label = (const int*)d_in[5];
    const float* th    = (const float*)d_in[6];
    float* out = (float*)d_out;

    float* accum  = (float*)d_ws;       // 8 floats:  [b*2+{in,grad}]
    float* boxacc = accum + 8;          // 80 floats: [box*2+{grad,in}]
    hipMemsetAsync(d_ws, 0, 88 * sizeof(float), stream);

    dim3 gA(3 * (HH / PR), BB);         // (240, 4)
    kglobal<<<gA, 256, 0, stream>>>(vis, th, gen, accum);

    dim3 gB(40, BB * NLB);              // 40 bands x 40 boxes
    kbox<<<gB, 256, 0, stream>>>(vis, th, gen, label, boxacc);

    kfin<<<1, 64, 0, stream>>>(accum, boxacc, label, bptr, cptr, out);
}

// Round 4
// 117.512 us; speedup vs baseline: 2.6203x; 1.1750x over previous
//
#include <hip/hip_runtime.h>

// Problem constants (fixed by setup_inputs)
#define BB    4
#define HH    640
#define WW    640
#define NLB   10
#define HWSZ  (HH * WW)      // 409600
#define BLK   128            // threads per block (2 waves)
#define PR    8              // rows per strip/band
#define GT    5              // column tiles per row: 5*128 = 640 exactly
#define GBANDS (HH / PR)     // 80 row bands
#define GPB   (GT * GBANDS)  // 400 global blocks per batch
#define GBLK  (GPB * BB)     // 1600 global blocks
#define BOXSLOTS 40          // band slots per box (bh <= 319 -> <= 40 bands)
#define XBLK  (BB * NLB * BOXSLOTS)  // 1600 box blocks

// Reduce (vin, vgr) across a 128-thread block; thread 0 stores to dst[0..1].
__device__ __forceinline__ void reduce2_write(float vin, float vgr,
                                              float* __restrict__ dst) {
    #pragma unroll
    for (int off = 32; off > 0; off >>= 1) {
        vin += __shfl_down(vin, off);
        vgr += __shfl_down(vgr, off);
    }
    __shared__ float s0[2], s1[2];
    const int lane = threadIdx.x & 63;
    const int w    = threadIdx.x >> 6;
    if (lane == 0) { s0[w] = vin; s1[w] = vgr; }
    __syncthreads();
    if (threadIdx.x == 0) {
        dst[0] = s0[0] + s0[1];
        dst[1] = s1[0] + s1[1];
    }
}

// |sobel| from three preloaded rows r0,r1,r2 of (L,C,R) triples
#define SOB(P, S) \
    (fabsf((P[S][2] - P[S][0]) + 2.0f * (P[S+1][2] - P[S+1][0]) + (P[S+2][2] - P[S+2][0])) + \
     fabsf((P[S][0] + 2.0f * P[S][1] + P[S][2]) - (P[S+2][0] + 2.0f * P[S+2][1] + P[S+2][2])))

// ---------------- Fused main kernel ----------------
// blocks [0, GBLK): global loss strips.  blocks [GBLK, GBLK+XBLK): box bands.
// Every block writes its 2 partial sums to a dedicated slot (no init needed).
__global__ __launch_bounds__(BLK) void kmain(const float* __restrict__ vis,
                                             const float* __restrict__ th,
                                             const float* __restrict__ gen,
                                             const int* __restrict__ label,
                                             float* __restrict__ gpart,
                                             float* __restrict__ xpart) {
    const int t = threadIdx.x;
    if (blockIdx.x < GBLK) {
        // ---- global phase: batch b, row band, column tile ----
        const int gid  = blockIdx.x;
        const int b    = gid / GPB;
        const int rem  = gid % GPB;
        const int band = rem / GT;
        const int xt   = rem % GT;
        const int c    = xt * BLK + t;      // [0, 640) — center always in image
        const int r0   = band * PR;
        const float* v = vis + b * HWSZ;
        const float* tp = th + b * HWSZ;
        const float* g = gen + b * HWSZ;
        const bool okL = (c >= 1);
        const bool okR = (c + 1 < WW);

        // Preload ALL rows first: 90 independent loads in flight.
        float rv[PR + 2][3], rt[PR + 2][3], rg[PR + 2][3];
        #pragma unroll
        for (int i = 0; i < PR + 2; ++i) {
            const int rr = r0 - 1 + i;
            const bool rok = ((unsigned)rr < (unsigned)HH);
            const int base = rr * WW + c;
            rv[i][0] = (rok && okL) ? v[base - 1]  : 0.0f;
            rv[i][1] =  rok         ? v[base]      : 0.0f;
            rv[i][2] = (rok && okR) ? v[base + 1]  : 0.0f;
            rt[i][0] = (rok && okL) ? tp[base - 1] : 0.0f;
            rt[i][1] =  rok         ? tp[base]     : 0.0f;
            rt[i][2] = (rok && okR) ? tp[base + 1] : 0.0f;
            rg[i][0] = (rok && okL) ? g[base - 1]  : 0.0f;
            rg[i][1] =  rok         ? g[base]      : 0.0f;
            rg[i][2] = (rok && okR) ? g[base + 1]  : 0.0f;
        }
        float t_in = 0.0f, t_gr = 0.0f;
        #pragma unroll
        for (int s = 0; s < PR; ++s) {
            float m[3][3];
            #pragma unroll
            for (int i = 0; i < 3; ++i)
                #pragma unroll
                for (int j = 0; j < 3; ++j)
                    m[i][j] = 0.5f * rv[s + i][j] + 0.5f * rt[s + i][j];
            const float sv = SOB(rv, s);
            const float sg = SOB(rg, s);
            const float sm = SOB(m, 0);
            t_gr += fabsf(sg - fmaxf(sv, sm));
            t_in += fabsf(rg[s + 1][1] - fmaxf(rv[s + 1][1], m[1][1]));
        }
        reduce2_write(t_in, t_gr, gpart + gid * 2);
    } else {
        // ---- box phase: box, band slot ----
        const int q    = blockIdx.x - GBLK;
        const int box  = q / BOXSLOTS;
        const int slot = q % BOXSLOTS;
        const int b    = box / NLB;
        const int* lb  = label + box * 5;
        const int x1 = lb[1], y1 = lb[2], x2 = lb[3], y2 = lb[4];
        const float* v = vis + b * HWSZ;
        const float* tp = th + b * HWSZ;
        const float* g = gen + b * HWSZ;
        float t_in = 0.0f, t_gr = 0.0f;
        for (int r0 = y1 + slot * PR; r0 < y2; r0 += BOXSLOTS * PR) {
            for (int cb = x1; cb < x2; cb += BLK) {
                const int c = cb + t;
                const bool okL = (c > x1) && (c - 1 < x2);  // left nb in box
                const bool okC = (c < x2);                  // center in box cols
                const bool okR = (c + 1 < x2);              // right nb in box
                float rv[PR + 2][3], rt[PR + 2][3], rg[PR + 2][3];
                #pragma unroll
                for (int i = 0; i < PR + 2; ++i) {
                    const int rr = r0 - 1 + i;
                    const bool rok = (rr >= y1) && (rr < y2);
                    const int base = rr * WW + c;
                    rv[i][0] = (rok && okL) ? v[base - 1]  : 0.0f;
                    rv[i][1] = (rok && okC) ? v[base]      : 0.0f;
                    rv[i][2] = (rok && okR) ? v[base + 1]  : 0.0f;
                    rt[i][0] = (rok && okL) ? tp[base - 1] : 0.0f;
                    rt[i][1] = (rok && okC) ? tp[base]     : 0.0f;
                    rt[i][2] = (rok && okR) ? tp[base + 1] : 0.0f;
                    rg[i][0] = (rok && okL) ? g[base - 1]  : 0.0f;
                    rg[i][1] = (rok && okC) ? g[base]      : 0.0f;
                    rg[i][2] = (rok && okR) ? g[base + 1]  : 0.0f;
                }
                #pragma unroll
                for (int s = 0; s < PR; ++s) {
                    // fmask: center pixel must lie inside the box
                    const float inb = (okC && (r0 + s < y2)) ? 1.0f : 0.0f;
                    float m[3][3];
                    #pragma unroll
                    for (int i = 0; i < 3; ++i)
                        #pragma unroll
                        for (int j = 0; j < 3; ++j)
                            m[i][j] = 0.3f * rv[s + i][j] + 0.7f * rt[s + i][j];
                    const float sv = SOB(rv, s);
                    const float sg = SOB(rg, s);
                    const float sm = SOB(m, 0);
                    t_gr += inb * fabsf(sg - fmaxf(sv, sm));
                    t_in += inb * fabsf(rg[s + 1][1] - fmaxf(rv[s + 1][1], m[1][1]));
                }
            }
        }
        reduce2_write(t_in, t_gr, xpart + q * 2);
    }
}

// ---------------- Finalize: reduce partials, compute all 7 outputs ----------
// out layout (flat, return order): loss_ss[4], loss_global[4], loss_label[4],
//                                  loss_in[4], loss_grad[4], ls[4], lin[4]
__global__ __launch_bounds__(256) void kfin(const float* __restrict__ gpart,
                                            const float* __restrict__ xpart,
                                            const int* __restrict__ label,
                                            const float* __restrict__ bptr,
                                            const float* __restrict__ cptr,
                                            float* __restrict__ out) {
    const int t = threadIdx.x;
    __shared__ float Sin[BB], Sgr[BB];
    __shared__ float Ls[BB * NLB], L1[BB * NLB];
    // global partial reduce: wave w = batch w, lanes stride over its 400 slots
    {
        const int w = t >> 6, l = t & 63;
        float a = 0.0f, gr = 0.0f;
        for (int j = l; j < GPB; j += 64) {
            a  += gpart[(w * GPB + j) * 2 + 0];
            gr += gpart[(w * GPB + j) * 2 + 1];
        }
        #pragma unroll
        for (int off = 32; off > 0; off >>= 1) {
            a  += __shfl_down(a, off);
            gr += __shfl_down(gr, off);
        }
        if (l == 0) { Sin[w] = a; Sgr[w] = gr; }
    }
    // per-box reduce over band slots + area/valid normalization
    if (t < BB * NLB) {
        float si = 0.0f, sg = 0.0f;
        for (int s = 0; s < BOXSLOTS; ++s) {
            si += xpart[(t * BOXSLOTS + s) * 2 + 0];
            sg += xpart[(t * BOXSLOTS + s) * 2 + 1];
        }
        const int* lb = label + t * 5;
        const int x1 = lb[1], y1 = lb[2], x2 = lb[3], y2 = lb[4];
        const bool valid = !((x1 == 0) && (y1 == 0) && (x2 == 0) && (y2 == 0));
        const float area = (float)((y2 - y1) * (x2 - x1));  // * C, C==1
        const float safe_area = fmaxf(area, 1.0f);
        const float vv = valid ? 1.0f : 0.0f;
        Ls[t] = sg / safe_area * vv;   // Lssim: gradient term
        L1[t] = si / safe_area * vv;   // L1loss: intensity term
    }
    __syncthreads();
    if (t < BB) {
        const float alpha = bptr[0];
        const float beta  = cptr[0];
        float cnt = 0.0f, sls = 0.0f, slin = 0.0f;
        for (int nl = 0; nl < NLB; nl++) {
            const float a = Ls[t * NLB + nl];
            const float l = L1[t * NLB + nl];
            if (a != 0.0f || l != 0.0f) cnt += 1.0f;
            sls  += a;
            slin += l;
        }
        const float safe_cnt = fmaxf(cnt, 1.0f);
        const float ls  = (cnt > 0.0f) ? (sls  / safe_cnt) : 0.0f;
        const float lin = (cnt > 0.0f) ? (slin / safe_cnt) : 0.0f;
        const float loss_label = (1.0f - beta) * ls + beta * lin;
        const float loss_in    = Sin[t] * (1.0f / (float)HWSZ);
        const float loss_grad  = Sgr[t] * (1.0f / (float)HWSZ);
        const float loss_global = alpha * loss_in + (1.0f - alpha) * loss_grad;
        out[0      + t] = 0.0f;          // loss_ss
        out[BB     + t] = loss_global;
        out[2 * BB + t] = loss_label;
        out[3 * BB + t] = loss_in;
        out[4 * BB + t] = loss_grad;
        out[5 * BB + t] = ls;
        out[6 * BB + t] = lin;
    }
}

extern "C" void kernel_launch(void* const* d_in, const int* in_sizes, int n_in,
                              void* d_out, int out_size, void* d_ws, size_t ws_size,
                              hipStream_t stream) {
    const float* bptr  = (const float*)d_in[0];
    const float* cptr  = (const float*)d_in[1];
    const float* vis   = (const float*)d_in[2];
    // d_in[3] = image_ir (unused by the reference)
    const float* gen   = (const float*)d_in[4];
    const int*   label = (const int*)d_in[5];
    const float* th    = (const float*)d_in[6];
    float* out = (float*)d_out;

    float* gpart = (float*)d_ws;            // GBLK*2 floats
    float* xpart = gpart + GBLK * 2;        // XBLK*2 floats
    // Every slot is written unconditionally by its block — no memset needed.

    kmain<<<GBLK + XBLK, BLK, 0, stream>>>(vis, th, gen, label, gpart, xpart);
    kfin<<<1, 256, 0, stream>>>(gpart, xpart, label, bptr, cptr, out);
}

// Round 5
// 105.067 us; speedup vs baseline: 2.9306x; 1.1185x over previous
//
#include <hip/hip_runtime.h>

// Problem constants (fixed by setup_inputs)
#define BB     4
#define HH     640
#define WW     640
#define NLB    10
#define HWSZ   (HH * WW)     // 409600
#define BLK    128           // threads per block (2 waves)
#define PRX    4             // rows per strip (both phases)
#define GXT    160           // float4 column tiles per row (640/4)
#define GBANDS 160           // row bands (640/4)
#define GSIDS  (BB * GBANDS * GXT)   // 102400 global strips
#define GBLKS  (GSIDS / BLK)         // 800 global blocks (200 per batch)
#define GPBB   (GBLKS / BB)          // 200 blocks per batch
#define SLOTS  40            // band slots per box (bh<=319 -> <=80 bands, 2 iters)
#define XBLKS  (BB * NLB * SLOTS)    // 1600 box blocks

// Reduce (vin, vgr) across a 128-thread block; thread 0 stores to dst[0..1].
__device__ __forceinline__ void reduce2_write(float vin, float vgr,
                                              float* __restrict__ dst) {
    #pragma unroll
    for (int off = 32; off > 0; off >>= 1) {
        vin += __shfl_down(vin, off);
        vgr += __shfl_down(vgr, off);
    }
    __shared__ float s0[2], s1[2];
    const int lane = threadIdx.x & 63;
    const int w    = threadIdx.x >> 6;
    if (lane == 0) { s0[w] = vin; s1[w] = vgr; }
    __syncthreads();
    if (threadIdx.x == 0) {
        dst[0] = s0[0] + s0[1];
        dst[1] = s1[0] + s1[1];
    }
}

// Process a 4-wide x PRX-tall strip with top-left center (c0, r0).
// Values outside [ry1,ry2) x [cx1,cx2) read as 0 (zero padding == mask).
// Only centers inside that rectangle accumulate (fmask).
// m-plane = w0*v + w1*t (sobel of m via linearity).
__device__ __forceinline__ void strip4(const float* __restrict__ v,
                                       const float* __restrict__ t,
                                       const float* __restrict__ g,
                                       int c0, int r0, int ry1, int ry2,
                                       int cx1, int cx2, float w0, float w1,
                                       float& s_in, float& s_gr) {
    // A[plane][row i][col j]; col j=0 is c0-1 .. j=5 is c0+4
    float A[3][PRX + 2][6];
    const int c4 = min(max(c0, 0), WW - 4);   // aligned float4 base (safe)
    const int cl = max(c0 - 1, 0);
    const int cr = min(c0 + 4, WW - 1);
    bool okc[6];
    #pragma unroll
    for (int j = 0; j < 6; ++j) {
        const int cc = c0 - 1 + j;
        okc[j] = (cc >= cx1) && (cc < cx2);
    }
    const float* P[3] = { v, t, g };
    #pragma unroll
    for (int i = 0; i < PRX + 2; ++i) {
        const int rr  = r0 - 1 + i;
        const bool rok = (rr >= ry1) && (rr < ry2);
        const int rb  = min(max(rr, 0), HH - 1) * WW;
        #pragma unroll
        for (int p = 0; p < 3; ++p) {
            const float4 f = *(const float4*)(P[p] + rb + c4);
            const float eL = P[p][rb + cl];
            const float eR = P[p][rb + cr];
            A[p][i][0] = (rok && okc[0]) ? eL  : 0.0f;
            A[p][i][1] = (rok && okc[1]) ? f.x : 0.0f;
            A[p][i][2] = (rok && okc[2]) ? f.y : 0.0f;
            A[p][i][3] = (rok && okc[3]) ? f.z : 0.0f;
            A[p][i][4] = (rok && okc[4]) ? f.w : 0.0f;
            A[p][i][5] = (rok && okc[5]) ? eR  : 0.0f;
        }
    }
    #pragma unroll
    for (int s = 0; s < PRX; ++s) {
        const int rc = r0 + s;                       // center row
        const bool rcin = (rc >= ry1) && (rc < ry2);
        #pragma unroll
        for (int c = 0; c < 4; ++c) {
            float gx[3], gy[3];
            #pragma unroll
            for (int p = 0; p < 3; ++p) {
                gx[p] = (A[p][s][c + 2] - A[p][s][c])
                      + 2.0f * (A[p][s + 1][c + 2] - A[p][s + 1][c])
                      + (A[p][s + 2][c + 2] - A[p][s + 2][c]);
                gy[p] = (A[p][s][c] + 2.0f * A[p][s][c + 1] + A[p][s][c + 2])
                      - (A[p][s + 2][c] + 2.0f * A[p][s + 2][c + 1] + A[p][s + 2][c + 2]);
            }
            const float sv  = fabsf(gx[0]) + fabsf(gy[0]);
            const float sg  = fabsf(gx[2]) + fabsf(gy[2]);
            const float gxm = w0 * gx[0] + w1 * gx[1];
            const float gym = w0 * gy[0] + w1 * gy[1];
            const float sm  = fabsf(gxm) + fabsf(gym);
            const float vc  = A[0][s + 1][c + 1];
            const float tc  = A[1][s + 1][c + 1];
            const float gc  = A[2][s + 1][c + 1];
            const float mc  = w0 * vc + w1 * tc;
            const float inb = (rcin && okc[c + 1]) ? 1.0f : 0.0f;
            s_gr += inb * fabsf(sg - fmaxf(sv, sm));
            s_in += inb * fabsf(gc - fmaxf(vc, mc));
        }
    }
}

// ---------------- Fused main kernel ----------------
// blocks [0, GBLKS): global strips.  blocks [GBLKS, GBLKS+XBLKS): box bands.
// Every block writes its 2 partial sums to a dedicated slot (no init needed).
__global__ __launch_bounds__(BLK) void kmain(const float* __restrict__ vis,
                                             const float* __restrict__ th,
                                             const float* __restrict__ gen,
                                             const int* __restrict__ label,
                                             float* __restrict__ gpart,
                                             float* __restrict__ xpart) {
    const int t = threadIdx.x;
    float s_in = 0.0f, s_gr = 0.0f;
    if (blockIdx.x < GBLKS) {
        // ---- global phase: sid -> (batch, band, xtile); lanes coalesced in xt
        const int sid  = blockIdx.x * BLK + t;
        const int xt   = sid % GXT;
        const int band = (sid / GXT) % GBANDS;
        const int b    = sid / (GXT * GBANDS);
        strip4(vis + b * HWSZ, th + b * HWSZ, gen + b * HWSZ,
               4 * xt, 4 * band, 0, HH, 0, WW, 0.5f, 0.5f, s_in, s_gr);
        reduce2_write(s_in, s_gr, gpart + blockIdx.x * 2);
    } else {
        // ---- box phase: (box, band slot) ----
        const int q    = blockIdx.x - GBLKS;
        const int box  = q / SLOTS;
        const int slot = q % SLOTS;
        const int b    = box / NLB;
        const int* lb  = label + box * 5;
        const int x1 = lb[1], y1 = lb[2], x2 = lb[3], y2 = lb[4];
        const int x1a = x1 & ~3;   // aligned start; cols < x1 are masked
        const float* v  = vis + b * HWSZ;
        const float* tp = th  + b * HWSZ;
        const float* g  = gen + b * HWSZ;
        for (int r0 = y1 + slot * PRX; r0 < y2; r0 += SLOTS * PRX)
            for (int cb = x1a; cb < x2; cb += BLK * 4)
                strip4(v, tp, g, cb + 4 * t, r0, y1, y2, x1, x2,
                       0.3f, 0.7f, s_in, s_gr);
        reduce2_write(s_in, s_gr, xpart + q * 2);
    }
}

// ---------------- Finalize: reduce partials, compute all 7 outputs ----------
// out layout (flat, return order): loss_ss[4], loss_global[4], loss_label[4],
//                                  loss_in[4], loss_grad[4], ls[4], lin[4]
__global__ __launch_bounds__(256) void kfin(const float* __restrict__ gpart,
                                            const float* __restrict__ xpart,
                                            const int* __restrict__ label,
                                            const float* __restrict__ bptr,
                                            const float* __restrict__ cptr,
                                            float* __restrict__ out) {
    const int t = threadIdx.x;
    __shared__ float Sin[BB], Sgr[BB];
    __shared__ float Ls[BB * NLB], L1[BB * NLB];
    // global partial reduce: wave w = batch w (blocks [GPBB*w, GPBB*(w+1)))
    {
        const int w = t >> 6, l = t & 63;
        float a = 0.0f, gr = 0.0f;
        for (int j = l; j < GPBB; j += 64) {
            a  += gpart[(w * GPBB + j) * 2 + 0];
            gr += gpart[(w * GPBB + j) * 2 + 1];
        }
        #pragma unroll
        for (int off = 32; off > 0; off >>= 1) {
            a  += __shfl_down(a, off);
            gr += __shfl_down(gr, off);
        }
        if (l == 0) { Sin[w] = a; Sgr[w] = gr; }
    }
    // per-box reduce over band slots + area/valid normalization
    if (t < BB * NLB) {
        float si = 0.0f, sg = 0.0f;
        for (int s = 0; s < SLOTS; ++s) {
            si += xpart[(t * SLOTS + s) * 2 + 0];
            sg += xpart[(t * SLOTS + s) * 2 + 1];
        }
        const int* lb = label + t * 5;
        const int x1 = lb[1], y1 = lb[2], x2 = lb[3], y2 = lb[4];
        const bool valid = !((x1 == 0) && (y1 == 0) && (x2 == 0) && (y2 == 0));
        const float area = (float)((y2 - y1) * (x2 - x1));  // * C, C==1
        const float safe_area = fmaxf(area, 1.0f);
        const float vv = valid ? 1.0f : 0.0f;
        Ls[t] = sg / safe_area * vv;   // Lssim: gradient term
        L1[t] = si / safe_area * vv;   // L1loss: intensity term
    }
    __syncthreads();
    if (t < BB) {
        const float alpha = bptr[0];
        const float beta  = cptr[0];
        float cnt = 0.0f, sls = 0.0f, slin = 0.0f;
        for (int nl = 0; nl < NLB; nl++) {
            const float a = Ls[t * NLB + nl];
            const float l = L1[t * NLB + nl];
            if (a != 0.0f || l != 0.0f) cnt += 1.0f;
            sls  += a;
            slin += l;
        }
        const float safe_cnt = fmaxf(cnt, 1.0f);
        const float ls  = (cnt > 0.0f) ? (sls  / safe_cnt) : 0.0f;
        const float lin = (cnt > 0.0f) ? (slin / safe_cnt) : 0.0f;
        const float loss_label = (1.0f - beta) * ls + beta * lin;
        const float loss_in    = Sin[t] * (1.0f / (float)HWSZ);
        const float loss_grad  = Sgr[t] * (1.0f / (float)HWSZ);
        const float loss_global = alpha * loss_in + (1.0f - alpha) * loss_grad;
        out[0      + t] = 0.0f;          // loss_ss
        out[BB     + t] = loss_global;
        out[2 * BB + t] = loss_label;
        out[3 * BB + t] = loss_in;
        out[4 * BB + t] = loss_grad;
        out[5 * BB + t] = ls;
        out[6 * BB + t] = lin;
    }
}

extern "C" void kernel_launch(void* const* d_in, const int* in_sizes, int n_in,
                              void* d_out, int out_size, void* d_ws, size_t ws_size,
                              hipStream_t stream) {
    const float* bptr  = (const float*)d_in[0];
    const float* cptr  = (const float*)d_in[1];
    const float* vis   = (const float*)d_in[2];
    // d_in[3] = image_ir (unused by the reference)
    const float* gen   = (const float*)d_in[4];
    const int*   label = (const int*)d_in[5];
    const float* th    = (const float*)d_in[6];
    float* out = (float*)d_out;

    float* gpart = (float*)d_ws;            // GBLKS*2 floats
    float* xpart = gpart + GBLKS * 2;       // XBLKS*2 floats
    // Every slot is written unconditionally by its block — no memset needed.

    kmain<<<GBLKS + XBLKS, BLK, 0, stream>>>(vis, th, gen, label, gpart, xpart);
    kfin<<<1, 256, 0, stream>>>(gpart, xpart, label, bptr, cptr, out);
}

// Round 6
// 102.473 us; speedup vs baseline: 3.0048x; 1.0253x over previous
//
#include <hip/hip_runtime.h>

// Problem constants (fixed by setup_inputs)
#define BB     4
#define HH     640
#define WW     640
#define NLB    10
#define HWSZ   (HH * WW)     // 409600
#define BLK    128           // threads per block (2 waves)
#define PRX    4             // rows per strip (both phases)
#define GXT    160           // float4 column tiles per row (640/4)
#define GBANDS 160           // row bands (640/4)
#define GSIDS  (BB * GBANDS * GXT)   // 102400 global strips
#define GBLKS  (GSIDS / BLK)         // 800 global blocks (200 per batch)
#define GPBB   (GBLKS / BB)          // 200 blocks per batch
#define SLOTS  20            // band slots per box; waves cover slot + w*SLOTS
#define XBLKS  (BB * NLB * SLOTS)    // 800 box blocks

// Reduce (vin, vgr) across a 128-thread block; thread 0 stores to dst[0..1].
__device__ __forceinline__ void reduce2_write(float vin, float vgr,
                                              float* __restrict__ dst) {
    #pragma unroll
    for (int off = 32; off > 0; off >>= 1) {
        vin += __shfl_down(vin, off);
        vgr += __shfl_down(vgr, off);
    }
    __shared__ float s0[2], s1[2];
    const int lane = threadIdx.x & 63;
    const int w    = threadIdx.x >> 6;
    if (lane == 0) { s0[w] = vin; s1[w] = vgr; }
    __syncthreads();
    if (threadIdx.x == 0) {
        dst[0] = s0[0] + s0[1];
        dst[1] = s1[0] + s1[1];
    }
}

// Process a 4-wide x PRX-tall strip with top-left center (c0, r0).
// Values outside [ry1,ry2) x [cx1,cx2) read as 0 (zero padding == mask).
// Only centers inside that rectangle accumulate (fmask).
// m-plane = w0*v + w1*t (sobel of m via linearity).
__device__ __forceinline__ void strip4(const float* __restrict__ v,
                                       const float* __restrict__ t,
                                       const float* __restrict__ g,
                                       int c0, int r0, int ry1, int ry2,
                                       int cx1, int cx2, float w0, float w1,
                                       float& s_in, float& s_gr) {
    // A[plane][row i][col j]; col j=0 is c0-1 .. j=5 is c0+4
    float A[3][PRX + 2][6];
    const int c4 = min(max(c0, 0), WW - 4);   // aligned float4 base (safe)
    const int cl = max(c0 - 1, 0);
    const int cr = min(c0 + 4, WW - 1);
    bool okc[6];
    #pragma unroll
    for (int j = 0; j < 6; ++j) {
        const int cc = c0 - 1 + j;
        okc[j] = (cc >= cx1) && (cc < cx2);
    }
    const float* P[3] = { v, t, g };
    #pragma unroll
    for (int i = 0; i < PRX + 2; ++i) {
        const int rr  = r0 - 1 + i;
        const bool rok = (rr >= ry1) && (rr < ry2);
        const int rb  = min(max(rr, 0), HH - 1) * WW;
        #pragma unroll
        for (int p = 0; p < 3; ++p) {
            const float4 f = *(const float4*)(P[p] + rb + c4);
            const float eL = P[p][rb + cl];
            const float eR = P[p][rb + cr];
            A[p][i][0] = (rok && okc[0]) ? eL  : 0.0f;
            A[p][i][1] = (rok && okc[1]) ? f.x : 0.0f;
            A[p][i][2] = (rok && okc[2]) ? f.y : 0.0f;
            A[p][i][3] = (rok && okc[3]) ? f.z : 0.0f;
            A[p][i][4] = (rok && okc[4]) ? f.w : 0.0f;
            A[p][i][5] = (rok && okc[5]) ? eR  : 0.0f;
        }
    }
    #pragma unroll
    for (int s = 0; s < PRX; ++s) {
        const int rc = r0 + s;                       // center row
        const bool rcin = (rc >= ry1) && (rc < ry2);
        #pragma unroll
        for (int c = 0; c < 4; ++c) {
            float gx[3], gy[3];
            #pragma unroll
            for (int p = 0; p < 3; ++p) {
                gx[p] = (A[p][s][c + 2] - A[p][s][c])
                      + 2.0f * (A[p][s + 1][c + 2] - A[p][s + 1][c])
                      + (A[p][s + 2][c + 2] - A[p][s + 2][c]);
                gy[p] = (A[p][s][c] + 2.0f * A[p][s][c + 1] + A[p][s][c + 2])
                      - (A[p][s + 2][c] + 2.0f * A[p][s + 2][c + 1] + A[p][s + 2][c + 2]);
            }
            const float sv  = fabsf(gx[0]) + fabsf(gy[0]);
            const float sg  = fabsf(gx[2]) + fabsf(gy[2]);
            const float gxm = w0 * gx[0] + w1 * gx[1];
            const float gym = w0 * gy[0] + w1 * gy[1];
            const float sm  = fabsf(gxm) + fabsf(gym);
            const float vc  = A[0][s + 1][c + 1];
            const float tc  = A[1][s + 1][c + 1];
            const float gc  = A[2][s + 1][c + 1];
            const float mc  = w0 * vc + w1 * tc;
            const float inb = (rcin && okc[c + 1]) ? 1.0f : 0.0f;
            s_gr += inb * fabsf(sg - fmaxf(sv, sm));
            s_in += inb * fabsf(gc - fmaxf(vc, mc));
        }
    }
}

// ---------------- Fused main kernel ----------------
// blocks [0, GBLKS): global strips.  blocks [GBLKS, GBLKS+XBLKS): box bands.
// Every block writes its 2 partial sums to a dedicated slot (no init needed).
__global__ __launch_bounds__(BLK) void kmain(const float* __restrict__ vis,
                                             const float* __restrict__ th,
                                             const float* __restrict__ gen,
                                             const int* __restrict__ label,
                                             float* __restrict__ gpart,
                                             float* __restrict__ xpart) {
    const int t = threadIdx.x;
    float s_in = 0.0f, s_gr = 0.0f;
    if (blockIdx.x < GBLKS) {
        // ---- global phase: sid -> (batch, band, xtile); lanes coalesced in xt
        const int sid  = blockIdx.x * BLK + t;
        const int xt   = sid % GXT;
        const int band = (sid / GXT) % GBANDS;
        const int b    = sid / (GXT * GBANDS);
        strip4(vis + b * HWSZ, th + b * HWSZ, gen + b * HWSZ,
               4 * xt, 4 * band, 0, HH, 0, WW, 0.5f, 0.5f, s_in, s_gr);
        reduce2_write(s_in, s_gr, gpart + blockIdx.x * 2);
    } else {
        // ---- box phase: block = (box, slot); wave w covers bands slot+w*SLOTS,
        //      stepping 2*SLOTS bands; 64-lane x 4-col (256-wide) column tiles.
        const int q    = blockIdx.x - GBLKS;
        const int box  = q / SLOTS;
        const int slot = q % SLOTS;
        const int b    = box / NLB;
        const int w    = t >> 6;
        const int lane = t & 63;
        const int* lb  = label + box * 5;
        const int x1 = lb[1], y1 = lb[2], x2 = lb[3], y2 = lb[4];
        const int x1a = x1 & ~3;   // aligned start; cols < x1 are masked
        const float* v  = vis + b * HWSZ;
        const float* tp = th  + b * HWSZ;
        const float* g  = gen + b * HWSZ;
        for (int r0 = y1 + (slot + w * SLOTS) * PRX; r0 < y2;
             r0 += 2 * SLOTS * PRX)
            for (int cb = x1a; cb < x2; cb += 64 * 4)
                strip4(v, tp, g, cb + 4 * lane, r0, y1, y2, x1, x2,
                       0.3f, 0.7f, s_in, s_gr);
        reduce2_write(s_in, s_gr, xpart + q * 2);
    }
}

// ---------------- Finalize: reduce partials, compute all 7 outputs ----------
// out layout (flat, return order): loss_ss[4], loss_global[4], loss_label[4],
//                                  loss_in[4], loss_grad[4], ls[4], lin[4]
__global__ __launch_bounds__(256) void kfin(const float* __restrict__ gpart,
                                            const float* __restrict__ xpart,
                                            const int* __restrict__ label,
                                            const float* __restrict__ bptr,
                                            const float* __restrict__ cptr,
                                            float* __restrict__ out) {
    const int t = threadIdx.x;
    __shared__ float Sin[BB], Sgr[BB];
    __shared__ float Ls[BB * NLB], L1[BB * NLB];
    // global partial reduce: wave w = batch w (blocks [GPBB*w, GPBB*(w+1)))
    {
        const int w = t >> 6, l = t & 63;
        float a = 0.0f, gr = 0.0f;
        for (int j = l; j < GPBB; j += 64) {
            a  += gpart[(w * GPBB + j) * 2 + 0];
            gr += gpart[(w * GPBB + j) * 2 + 1];
        }
        #pragma unroll
        for (int off = 32; off > 0; off >>= 1) {
            a  += __shfl_down(a, off);
            gr += __shfl_down(gr, off);
        }
        if (l == 0) { Sin[w] = a; Sgr[w] = gr; }
    }
    // per-box reduce over band slots + area/valid normalization
    if (t < BB * NLB) {
        float si = 0.0f, sg = 0.0f;
        #pragma unroll
        for (int s = 0; s < SLOTS; ++s) {
            si += xpart[(t * SLOTS + s) * 2 + 0];
            sg += xpart[(t * SLOTS + s) * 2 + 1];
        }
        const int* lb = label + t * 5;
        const int x1 = lb[1], y1 = lb[2], x2 = lb[3], y2 = lb[4];
        const bool valid = !((x1 == 0) && (y1 == 0) && (x2 == 0) && (y2 == 0));
        const float area = (float)((y2 - y1) * (x2 - x1));  // * C, C==1
        const float safe_area = fmaxf(area, 1.0f);
        const float vv = valid ? 1.0f : 0.0f;
        Ls[t] = sg / safe_area * vv;   // Lssim: gradient term
        L1[t] = si / safe_area * vv;   // L1loss: intensity term
    }
    __syncthreads();
    if (t < BB) {
        const float alpha = bptr[0];
        const float beta  = cptr[0];
        float cnt = 0.0f, sls = 0.0f, slin = 0.0f;
        for (int nl = 0; nl < NLB; nl++) {
            const float a = Ls[t * NLB + nl];
            const float l = L1[t * NLB + nl];
            if (a != 0.0f || l != 0.0f) cnt += 1.0f;
            sls  += a;
            slin += l;
        }
        const float safe_cnt = fmaxf(cnt, 1.0f);
        const float ls  = (cnt > 0.0f) ? (sls  / safe_cnt) : 0.0f;
        const float lin = (cnt > 0.0f) ? (slin / safe_cnt) : 0.0f;
        const float loss_label = (1.0f - beta) * ls + beta * lin;
        const float loss_in    = Sin[t] * (1.0f / (float)HWSZ);
        const float loss_grad  = Sgr[t] * (1.0f / (float)HWSZ);
        const float loss_global = alpha * loss_in + (1.0f - alpha) * loss_grad;
        out[0      + t] = 0.0f;          // loss_ss
        out[BB     + t] = loss_global;
        out[2 * BB + t] = loss_label;
        out[3 * BB + t] = loss_in;
        out[4 * BB + t] = loss_grad;
        out[5 * BB + t] = ls;
        out[6 * BB + t] = lin;
    }
}

extern "C" void kernel_launch(void* const* d_in, const int* in_sizes, int n_in,
                              void* d_out, int out_size, void* d_ws, size_t ws_size,
                              hipStream_t stream) {
    const float* bptr  = (const float*)d_in[0];
    const float* cptr  = (const float*)d_in[1];
    const float* vis   = (const float*)d_in[2];
    // d_in[3] = image_ir (unused by the reference)
    const float* gen   = (const float*)d_in[4];
    const int*   label = (const int*)d_in[5];
    const float* th    = (const float*)d_in[6];
    float* out = (float*)d_out;

    float* gpart = (float*)d_ws;            // GBLKS*2 floats
    float* xpart = gpart + GBLKS * 2;       // XBLKS*2 floats
    // Every slot is written unconditionally by its block — no memset needed.

    kmain<<<GBLKS + XBLKS, BLK, 0, stream>>>(vis, th, gen, label, gpart, xpart);
    kfin<<<1, 256, 0, stream>>>(gpart, xpart, label, bptr, cptr, out);
}